// Round 1
// baseline (121.587 us; speedup 1.0000x reference)
//
#include <hip/hip_runtime.h>

// Problem constants (B,C,H,W)=(32,32,64,64), D=32, K=512
#define C_    32
#define D_    32
#define K_    512
#define HW_   4096
#define NTOK  131072           // B*H*W
#define OUT_ELEMS 4194304      // B*C*H*W
#define IDX_OFF   4194304
#define LOSS_OFF  4325376      // OUT_ELEMS + NTOK

__global__ __launch_bounds__(256)
void vq_fused(const float* __restrict__ z,
              const float* __restrict__ qw,    // (D,C)
              const float* __restrict__ qb,    // (D)
              const float* __restrict__ cb,    // (K,D)
              const float* __restrict__ pw,    // (C,D)
              const float* __restrict__ pb,    // (C)
              float* __restrict__ out)         // full d_out (f32)
{
    __shared__ float cbn[K_];
    __shared__ float lsum[4];

    const int tid = threadIdx.x;

    // ---- per-block: codebook squared norms into LDS ----
    for (int k = tid; k < K_; k += 256) {
        const float* row = cb + k * D_;
        float s = 0.f;
        #pragma unroll
        for (int d = 0; d < D_; ++d) s = fmaf(row[d], row[d], s);
        cbn[k] = s;
    }
    __syncthreads();

    const int token = blockIdx.x * 256 + tid;
    const int b  = token >> 12;           // / HW_
    const int hw = token & (HW_ - 1);

    // ---- load z channels (coalesced per-c) ----
    const float* zbase = z + (size_t)b * C_ * HW_ + hw;
    float zv[C_];
    #pragma unroll
    for (int c = 0; c < C_; ++c) zv[c] = zbase[(size_t)c * HW_];

    // ---- quant conv: xf[d] = qb[d] + sum_c zv[c]*qw[d,c] (qw via scalar loads) ----
    float xf[D_];
    #pragma unroll
    for (int d = 0; d < D_; ++d) {
        float a = qb[d];
        #pragma unroll
        for (int c = 0; c < C_; ++c) a = fmaf(zv[c], qw[d * C_ + c], a);
        xf[d] = a;
    }

    // ---- nearest codebook entry: argmin_k (||c_k||^2 - 2 x.c_k) ----
    float best = 3.4e38f;
    int   bi   = 0;
    #pragma unroll 2
    for (int k = 0; k < K_; ++k) {
        const float* row = cb + k * D_;   // k is wave-uniform -> s_load path
        float p0 = 0.f, p1 = 0.f, p2 = 0.f, p3 = 0.f;
        #pragma unroll
        for (int d = 0; d < D_; d += 4) {
            p0 = fmaf(xf[d + 0], row[d + 0], p0);
            p1 = fmaf(xf[d + 1], row[d + 1], p1);
            p2 = fmaf(xf[d + 2], row[d + 2], p2);
            p3 = fmaf(xf[d + 3], row[d + 3], p3);
        }
        const float dot = (p0 + p1) + (p2 + p3);
        const float s   = fmaf(-2.f, dot, cbn[k]);
        if (s < best) { best = s; bi = k; }   // strict < keeps first min (jnp semantics)
    }

    // idx output (as float; exact for 0..511)
    out[IDX_OFF + token] = (float)bi;

    // ---- gather chosen code (per-lane, L1/L2-resident) ----
    const float* qrow = cb + (size_t)bi * D_;
    float q[D_];
    #pragma unroll
    for (int d = 0; d < D_; ++d) q[d] = qrow[d];

    // ---- loss partial: sum (q-x)^2 ----
    float l = 0.f;
    #pragma unroll
    for (int d = 0; d < D_; ++d) { const float df = q[d] - xf[d]; l = fmaf(df, df, l); }

    // ---- post_quant conv: out[c] = pb[c] + sum_d q[d]*pw[c,d] ----
    float* obase = out + (size_t)b * C_ * HW_ + hw;
    #pragma unroll
    for (int c = 0; c < C_; ++c) {
        float a = pb[c];
        #pragma unroll
        for (int d = 0; d < D_; ++d) a = fmaf(q[d], pw[c * D_ + d], a);
        obase[(size_t)c * HW_] = a;
    }

    // ---- loss reduction: wave shfl -> block -> one atomic per block ----
    #pragma unroll
    for (int off = 32; off > 0; off >>= 1) l += __shfl_down(l, off);
    const int wid = tid >> 6, lane = tid & 63;
    if (lane == 0) lsum[wid] = l;
    __syncthreads();
    if (tid == 0) {
        const float t = (lsum[0] + lsum[1]) + (lsum[2] + lsum[3]);
        // loss = commit + cb_loss = 2 * mean((q-x)^2) over NTOK*D elements
        atomicAdd(out + LOSS_OFF, t * (2.0f / (float)(NTOK * D_)));
    }
}

extern "C" void kernel_launch(void* const* d_in, const int* in_sizes, int n_in,
                              void* d_out, int out_size, void* d_ws, size_t ws_size,
                              hipStream_t stream) {
    (void)in_sizes; (void)n_in; (void)d_ws; (void)ws_size; (void)out_size;
    const float* z  = (const float*)d_in[0];
    const float* qw = (const float*)d_in[1];
    const float* qb = (const float*)d_in[2];
    const float* cb = (const float*)d_in[3];
    const float* pw = (const float*)d_in[4];
    const float* pb = (const float*)d_in[5];
    float* out = (float*)d_out;

    // zero the loss accumulator slot (graph-capture safe)
    hipMemsetAsync((char*)d_out + (size_t)LOSS_OFF * sizeof(float), 0, sizeof(float), stream);

    vq_fused<<<NTOK / 256, 256, 0, stream>>>(z, qw, qb, cb, pw, pb, out);
}